// Round 2
// baseline (274.133 us; speedup 1.0000x reference)
//
#include <hip/hip_runtime.h>
#include <hip/hip_bf16.h>

#define B_ 4
#define T_ 2048
#define C_ 1024
#define H_ 16
#define D_ 64

typedef __attribute__((ext_vector_type(8))) short short8;
typedef __attribute__((ext_vector_type(4))) float f32x4;

// q pre-scale: (1/sqrt(D)) * log2(e) so attn uses raw v_exp_f32 (exp2)
#define QSCALE 0.18033688011112042f

static __device__ __forceinline__ unsigned short f2bf(float f) {
  unsigned u = __float_as_uint(f);
  u += 0x7fff + ((u >> 16) & 1);  // round-to-nearest-even
  return (unsigned short)(u >> 16);
}

// packed bf16 convert: dword = {bf16(lo), bf16(hi)<<16}, RNE (T12 primitive)
static __device__ __forceinline__ unsigned cvt_pk_bf16(float lo, float hi) {
  unsigned r;
  asm("v_cvt_pk_bf16_f32 %0, %1, %2" : "=v"(r) : "v"(lo), "v"(hi));
  return r;
}

static __device__ __forceinline__ float fast_exp2(float x) {
#if __has_builtin(__builtin_amdgcn_exp2f)
  return __builtin_amdgcn_exp2f(x);
#else
  return exp2f(x);
#endif
}

#define GL2LDS16(g, l)                                              \
  __builtin_amdgcn_global_load_lds(                                 \
      (const __attribute__((address_space(1))) void*)(g),           \
      (__attribute__((address_space(3))) void*)(l), 16, 0, 0)

// ---------------------------------------------------------------------------
// Fused pre-pass: x->bf16 (blocks 0..8191), Wqkv transpose (8192..11263),
// Wproj transpose (11264..12287).
// ---------------------------------------------------------------------------
__global__ __launch_bounds__(256) void prepass(
    const float* __restrict__ x, const float* __restrict__ Wq,
    const float* __restrict__ Wp, ushort* __restrict__ xb,
    ushort* __restrict__ Wqt, ushort* __restrict__ Wpt) {
  __shared__ ushort tile[32][33];
  const int bid = blockIdx.x;
  if (bid < 8192) {
    const size_t i = ((size_t)bid * 256 + threadIdx.x) * 4;
    float4 vv = *(const float4*)(x + i);
    ushort4 o = {f2bf(vv.x), f2bf(vv.y), f2bf(vv.z), f2bf(vv.w)};
    *(ushort4*)(xb + i) = o;
    return;
  }
  const float* in;
  ushort* out;
  int N, tix;
  if (bid < 8192 + 3072) {
    in = Wq; out = Wqt; N = 3 * C_; tix = bid - 8192;
  } else {
    in = Wp; out = Wpt; N = C_; tix = bid - 11264;
  }
  const int nT = N >> 5;
  const int k0 = (tix / nT) << 5, n0 = (tix % nT) << 5;
  const int r = threadIdx.x >> 3;
  const int c4 = (threadIdx.x & 7) << 2;
  float4 v = *(const float4*)(in + (size_t)(k0 + r) * N + n0 + c4);
  tile[c4 + 0][r] = f2bf(v.x);
  tile[c4 + 1][r] = f2bf(v.y);
  tile[c4 + 2][r] = f2bf(v.z);
  tile[c4 + 3][r] = f2bf(v.w);
  __syncthreads();
  ushort4 o = {tile[r][c4], tile[r][c4 + 1], tile[r][c4 + 2], tile[r][c4 + 3]};
  *(ushort4*)(out + (size_t)(n0 + r) * C_ + k0 + c4) = o;
}

// ---------------------------------------------------------------------------
// LDS XOR-swizzle for BK=64 tiles (128 rows x 128 B). Chunk (16 B) at row r,
// position pos holds global k-chunk x = pos ^ (r & 7).
// ---------------------------------------------------------------------------
static __device__ __forceinline__ void swz_src64(int wave, int lane, int p,
                                                 int& row, int& offU) {
  const int flat = p * 4096 + wave * 1024 + lane * 16;  // byte offset in tile
  row = flat >> 7;                    // 128 B per row
  const int pos = (flat & 127) >> 4;  // chunk index in row
  const int x = pos ^ (row & 7);
  offU = x * 8;  // ushort offset within the global row's K-span
}
static __device__ __forceinline__ int swz_frag64(int r, int quad, int ko) {
  return r * 128 + (((quad | (ko << 2)) ^ (r & 7)) << 4);  // bytes
}

// ---------------------------------------------------------------------------
// MFMA GEMM 1: qkv. q,k -> [B,H,T,D] bf16 (q pre-scaled); v -> [B,H,D,T].
// XCD-aware bijective block swizzle (T1): nwg=1536, 192 tiles per XCD chunk.
// ---------------------------------------------------------------------------
__global__ __launch_bounds__(256) void gemm_qkv_mfma(
    const ushort* __restrict__ A, const ushort* __restrict__ Bt,
    const float* __restrict__ bias, ushort* __restrict__ q,
    ushort* __restrict__ k, ushort* __restrict__ v) {
  __shared__ __align__(16) ushort As[128 * 64];
  __shared__ __align__(16) ushort Bs[128 * 64];
  const int tid = threadIdx.x;
  const int wave = tid >> 6, lane = tid & 63;
  const int c = lane & 15, quad = lane >> 4;
  const int wm = wave & 1, wn = wave >> 1;
  const int bid0 = blockIdx.y * 24 + blockIdx.x;
  const int bid = (bid0 & 7) * 192 + (bid0 >> 3);  // XCD chunking, bijective
  const int m0 = (bid / 24) << 7;
  const int n0 = (bid % 24) << 7;

  int sRow[4], sOff[4];
#pragma unroll
  for (int p = 0; p < 4; ++p) swz_src64(wave, lane, p, sRow[p], sOff[p]);
  int fOffA[2][4], fOffB[2][4];
#pragma unroll
  for (int ko = 0; ko < 2; ++ko) {
#pragma unroll
    for (int i = 0; i < 4; ++i)
      fOffA[ko][i] = swz_frag64(wm * 64 + i * 16 + c, quad, ko);
#pragma unroll
    for (int j = 0; j < 4; ++j)
      fOffB[ko][j] = swz_frag64(wn * 64 + j * 16 + c, quad, ko);
  }

  f32x4 acc[4][4];
#pragma unroll
  for (int i = 0; i < 4; ++i)
#pragma unroll
    for (int j = 0; j < 4; ++j) acc[i][j] = (f32x4){0.f, 0.f, 0.f, 0.f};

  for (int k0 = 0; k0 < C_; k0 += 64) {
    __syncthreads();
#pragma unroll
    for (int p = 0; p < 4; ++p) {
      GL2LDS16(A + (size_t)(m0 + sRow[p]) * C_ + k0 + sOff[p],
               (char*)As + p * 4096 + wave * 1024);
      GL2LDS16(Bt + (size_t)(n0 + sRow[p]) * C_ + k0 + sOff[p],
               (char*)Bs + p * 4096 + wave * 1024);
    }
    __syncthreads();
#pragma unroll
    for (int ko = 0; ko < 2; ++ko) {
      short8 af[4], bf[4];
#pragma unroll
      for (int i = 0; i < 4; ++i)
        af[i] = *(const short8*)((const char*)As + fOffA[ko][i]);
#pragma unroll
      for (int j = 0; j < 4; ++j)
        bf[j] = *(const short8*)((const char*)Bs + fOffB[ko][j]);
#pragma unroll
      for (int i = 0; i < 4; ++i)
#pragma unroll
        for (int j = 0; j < 4; ++j)
          acc[i][j] = __builtin_amdgcn_mfma_f32_16x16x32_bf16(af[i], bf[j],
                                                              acc[i][j], 0, 0, 0);
    }
  }

  const int s = n0 >> 10;  // uniform per block
  if (s == 2) {
    // v epilogue: [B,H,D,T], reg r spans 4 consecutive t -> ushort4
#pragma unroll
    for (int j = 0; j < 4; ++j) {
      const int n = n0 + wn * 64 + j * 16 + c;
      const int h = (n >> 6) & 15, d = n & 63;
      const float bval = bias[n];
#pragma unroll
      for (int i = 0; i < 4; ++i) {
        const int m = m0 + wm * 64 + i * 16 + quad * 4;
        const int b = m >> 11, t = m & 2047;
        ushort4 pk = {f2bf(acc[i][j][0] + bval), f2bf(acc[i][j][1] + bval),
                      f2bf(acc[i][j][2] + bval), f2bf(acc[i][j][3] + bval)};
        *(ushort4*)(v + (((size_t)((b << 4) + h) << 6) + d) * T_ + t) = pk;
      }
    }
  } else {
    ushort* outp = (s == 0) ? q : k;
    const float sc = (s == 0) ? QSCALE : 1.0f;
#pragma unroll
    for (int j = 0; j < 4; ++j) {
      const int n = n0 + wn * 64 + j * 16 + c;
      const int h = (n >> 6) & 15, d = n & 63;
      const float bval = bias[n];
#pragma unroll
      for (int i = 0; i < 4; ++i) {
#pragma unroll
        for (int r = 0; r < 4; ++r) {
          const int m = m0 + wm * 64 + i * 16 + quad * 4 + r;
          const int b = m >> 11, t = m & 2047;
          outp[(((size_t)((b << 4) + h) << 11) + t) * 64 + d] =
              f2bf((acc[i][j][r] + bval) * sc);
        }
      }
    }
  }
}

// ---------------------------------------------------------------------------
// MFMA GEMM 2: out = y2 @ Wproj + bproj (fp32 out). BK=64, grid (8, 64).
// XCD-aware bijective block swizzle: nwg=512, 64 tiles per XCD chunk.
// ---------------------------------------------------------------------------
__global__ __launch_bounds__(256) void gemm_proj_mfma(
    const ushort* __restrict__ A, const ushort* __restrict__ Bt,
    const float* __restrict__ bias, float* __restrict__ out) {
  __shared__ __align__(16) ushort As[128 * 64];
  __shared__ __align__(16) ushort Bs[128 * 64];
  const int tid = threadIdx.x;
  const int wave = tid >> 6, lane = tid & 63;
  const int c = lane & 15, quad = lane >> 4;
  const int wm = wave & 1, wn = wave >> 1;
  const int bid0 = blockIdx.y * 8 + blockIdx.x;
  const int bid = (bid0 & 7) * 64 + (bid0 >> 3);  // XCD chunking, bijective
  const int m0 = (bid >> 3) << 7;
  const int n0 = (bid & 7) << 7;

  int sRow[4], sOff[4];
#pragma unroll
  for (int p = 0; p < 4; ++p) swz_src64(wave, lane, p, sRow[p], sOff[p]);
  int fOffA[2][4], fOffB[2][4];
#pragma unroll
  for (int ko = 0; ko < 2; ++ko) {
#pragma unroll
    for (int i = 0; i < 4; ++i)
      fOffA[ko][i] = swz_frag64(wm * 64 + i * 16 + c, quad, ko);
#pragma unroll
    for (int j = 0; j < 4; ++j)
      fOffB[ko][j] = swz_frag64(wn * 64 + j * 16 + c, quad, ko);
  }

  f32x4 acc[4][4];
#pragma unroll
  for (int i = 0; i < 4; ++i)
#pragma unroll
    for (int j = 0; j < 4; ++j) acc[i][j] = (f32x4){0.f, 0.f, 0.f, 0.f};

  for (int k0 = 0; k0 < C_; k0 += 64) {
    __syncthreads();
#pragma unroll
    for (int p = 0; p < 4; ++p) {
      GL2LDS16(A + (size_t)(m0 + sRow[p]) * C_ + k0 + sOff[p],
               (char*)As + p * 4096 + wave * 1024);
      GL2LDS16(Bt + (size_t)(n0 + sRow[p]) * C_ + k0 + sOff[p],
               (char*)Bs + p * 4096 + wave * 1024);
    }
    __syncthreads();
#pragma unroll
    for (int ko = 0; ko < 2; ++ko) {
      short8 af[4], bf[4];
#pragma unroll
      for (int i = 0; i < 4; ++i)
        af[i] = *(const short8*)((const char*)As + fOffA[ko][i]);
#pragma unroll
      for (int j = 0; j < 4; ++j)
        bf[j] = *(const short8*)((const char*)Bs + fOffB[ko][j]);
#pragma unroll
      for (int i = 0; i < 4; ++i)
#pragma unroll
        for (int j = 0; j < 4; ++j)
          acc[i][j] = __builtin_amdgcn_mfma_f32_16x16x32_bf16(af[i], bf[j],
                                                              acc[i][j], 0, 0, 0);
    }
  }

#pragma unroll
  for (int j = 0; j < 4; ++j) {
    const int n = n0 + wn * 64 + j * 16 + c;
    const float bval = bias[n];
#pragma unroll
    for (int i = 0; i < 4; ++i) {
#pragma unroll
      for (int r = 0; r < 4; ++r) {
        const int m = m0 + wm * 64 + i * 16 + quad * 4 + r;
        out[(size_t)m * C_ + n] = acc[i][j][r] + bval;
      }
    }
  }
}

// ---------------------------------------------------------------------------
// Flash attention v6: causal-paired blocks. Block pi handles q-tiles
// qtA = pi (short) and qtB = 15-pi (long): every block does exactly 34
// KV-tile compute units -> perfect load balance at 2 blocks/CU (512 blocks,
// all resident). K/V staged ONCE per tile for both halves; K-frag and
// V-frag LDS reads shared across halves.
// ---------------------------------------------------------------------------
__global__ __launch_bounds__(256) void attn(const ushort* __restrict__ q,
                                            const ushort* __restrict__ k,
                                            const ushort* __restrict__ v,
                                            ushort* __restrict__ y2) {
  const int pi = blockIdx.x >> 6;  // 0..7
  const int bh = blockIdx.x & 63;
  const int qtA = pi, qtB = 15 - pi;
  const int t0A = qtA << 7, t0B = qtB << 7;
  const int w = threadIdx.x >> 6;
  const int lane = threadIdx.x & 63;
  const int c = lane & 15;
  const int quad = lane >> 4;

  const ushort* qp = q + (size_t)bh * T_ * D_;
  const ushort* kp = k + (size_t)bh * T_ * D_;
  const ushort* vp = v + (size_t)bh * D_ * T_;  // [d][t]

  __shared__ __align__(16) ushort Ks[64][72];     // [key][d]
  __shared__ __align__(16) ushort Vs[64][72];     // [d][key]
  __shared__ __align__(16) ushort Ps[4][32][72];  // per-wave [query][key]

  short8 qfA[2][2], qfB[2][2];
#pragma unroll
  for (int g = 0; g < 2; ++g) {
    const ushort* qa = qp + (size_t)(t0A + 32 * w + 16 * g + c) * D_;
    const ushort* qb = qp + (size_t)(t0B + 32 * w + 16 * g + c) * D_;
    qfA[g][0] = *(const short8*)(qa + quad * 8);
    qfA[g][1] = *(const short8*)(qa + 32 + quad * 8);
    qfB[g][0] = *(const short8*)(qb + quad * 8);
    qfB[g][1] = *(const short8*)(qb + 32 + quad * 8);
  }

  const int srow = threadIdx.x >> 2;
  const int soff = (threadIdx.x & 3) << 4;

  uint4 ka, kb, va, vb;  // prefetch tile 0
  {
    const ushort* ks = kp + (size_t)srow * D_ + soff;
    const ushort* vs = vp + (size_t)srow * T_ + soff;
    ka = *(const uint4*)(ks);
    kb = *(const uint4*)(ks + 8);
    va = *(const uint4*)(vs);
    vb = *(const uint4*)(vs + 8);
  }

  f32x4 oA[2][4], oB[2][4];
  float lA[2] = {0.f, 0.f}, lB[2] = {0.f, 0.f};
#pragma unroll
  for (int g = 0; g < 2; ++g)
#pragma unroll
    for (int dt = 0; dt < 4; ++dt) {
      oA[g][dt] = (f32x4){0.f, 0.f, 0.f, 0.f};
      oB[g][dt] = (f32x4){0.f, 0.f, 0.f, 0.f};
    }

  const int nbA = 2 * qtA + 2;
  const int nbB = 2 * qtB + 2;

// S^T = K Q^T for one half (K-frags re-read from LDS, cheap)
#define QK_HALF(qf, st)                                                        \
  do {                                                                         \
    __builtin_amdgcn_s_setprio(1);                                             \
    _Pragma("unroll") for (int kt = 0; kt < 4; ++kt) {                         \
      short8 af0 = *(const short8*)(&Ks[kt * 16 + c][quad * 8]);               \
      short8 af1 = *(const short8*)(&Ks[kt * 16 + c][32 + quad * 8]);          \
      _Pragma("unroll") for (int g = 0; g < 2; ++g) {                          \
        f32x4 a = (f32x4){0.f, 0.f, 0.f, 0.f};                                 \
        a = __builtin_amdgcn_mfma_f32_16x16x32_bf16(af0, qf[g][0], a, 0, 0, 0);\
        a = __builtin_amdgcn_mfma_f32_16x16x32_bf16(af1, qf[g][1], a, 0, 0, 0);\
        st[g][kt] = a;                                                         \
      }                                                                        \
    }                                                                          \
    __builtin_amdgcn_s_setprio(0);                                             \
  } while (0)

// mask + exp2 + pack to Ps for one half
#define SM_HALF(st, t0X, lX)                                                   \
  do {                                                                         \
    _Pragma("unroll") for (int g = 0; g < 2; ++g) {                            \
      const int qbase = t0X + 32 * w + 16 * g;                                 \
      if (s0 + 63 > qbase) {                                                   \
        _Pragma("unroll") for (int kt = 0; kt < 4; ++kt)                       \
            _Pragma("unroll") for (int r = 0; r < 4; ++r) if (                 \
                s0 + kt * 16 + 4 * quad + r > qbase + c) st[g][kt][r] = -1e30f;\
      }                                                                        \
      float lacc = 0.f;                                                        \
      _Pragma("unroll") for (int kt = 0; kt < 4; ++kt) {                       \
        float p0 = fast_exp2(st[g][kt][0]);                                    \
        float p1 = fast_exp2(st[g][kt][1]);                                    \
        float p2 = fast_exp2(st[g][kt][2]);                                    \
        float p3 = fast_exp2(st[g][kt][3]);                                    \
        lacc += (p0 + p1) + (p2 + p3);                                         \
        uint2 pw = {cvt_pk_bf16(p0, p1), cvt_pk_bf16(p2, p3)};                 \
        *(uint2*)(&Ps[w][g * 16 + c][kt * 16 + 4 * quad]) = pw;                \
      }                                                                        \
      lX[g] += lacc;                                                           \
    }                                                                          \
  } while (0)

#define PF_READ(pf)                                                            \
  do {                                                                         \
    _Pragma("unroll") for (int g = 0; g < 2; ++g) {                            \
      pf[g][0] = *(const short8*)(&Ps[w][g * 16 + c][quad * 8]);               \
      pf[g][1] = *(const short8*)(&Ps[w][g * 16 + c][32 + quad * 8]);          \
    }                                                                          \
  } while (0)

  for (int ib = 0; ib < nbB; ++ib) {
    const int s0 = ib << 6;
    const bool actA = ib < nbA;  // block-uniform
    __syncthreads();
    *(uint4*)(&Ks[srow][soff]) = ka;
    *(uint4*)(&Ks[srow][soff + 8]) = kb;
    *(uint4*)(&Vs[srow][soff]) = va;
    *(uint4*)(&Vs[srow][soff + 8]) = vb;
    __syncthreads();

    if (ib + 1 < nbB) {  // prefetch next tile (overlaps compute)
      const int s1 = (ib + 1) << 6;
      const ushort* ks = kp + (size_t)(s1 + srow) * D_ + soff;
      const ushort* vs = vp + (size_t)srow * T_ + s1 + soff;
      ka = *(const uint4*)(ks);
      kb = *(const uint4*)(ks + 8);
      va = *(const uint4*)(vs);
      vb = *(const uint4*)(vs + 8);
    }

    // ---- half B (always active) ----
    f32x4 st[2][4];
    QK_HALF(qfB, st);
    SM_HALF(st, t0B, lB);
    short8 pfB[2][2];
    PF_READ(pfB);

    // ---- half A (first nbA tiles only; Ps reused after pfB is in regs) ----
    short8 pfA[2][2];
    if (actA) {
      QK_HALF(qfA, st);
      SM_HALF(st, t0A, lA);
      PF_READ(pfA);
    }

    // ---- O^T += V^T P^T; V-frags shared across halves and q-groups ----
    __builtin_amdgcn_s_setprio(1);
    if (actA) {
#pragma unroll
      for (int dt = 0; dt < 4; ++dt) {
        short8 vf0 = *(const short8*)(&Vs[dt * 16 + c][quad * 8]);
        short8 vf1 = *(const short8*)(&Vs[dt * 16 + c][32 + quad * 8]);
#pragma unroll
        for (int g = 0; g < 2; ++g) {
          oB[g][dt] = __builtin_amdgcn_mfma_f32_16x16x32_bf16(vf0, pfB[g][0],
                                                              oB[g][dt], 0, 0, 0);
          oB[g][dt] = __builtin_amdgcn_mfma_f32_16x16x32_bf16(vf1, pfB[g][1],
                                                              oB[g][dt], 0, 0, 0);
          oA[g][dt] = __builtin_amdgcn_mfma_f32_16x16x32_bf16(vf0, pfA[g][0],
                                                              oA[g][dt], 0, 0, 0);
          oA[g][dt] = __builtin_amdgcn_mfma_f32_16x16x32_bf16(vf1, pfA[g][1],
                                                              oA[g][dt], 0, 0, 0);
        }
      }
    } else {
#pragma unroll
      for (int dt = 0; dt < 4; ++dt) {
        short8 vf0 = *(const short8*)(&Vs[dt * 16 + c][quad * 8]);
        short8 vf1 = *(const short8*)(&Vs[dt * 16 + c][32 + quad * 8]);
#pragma unroll
        for (int g = 0; g < 2; ++g) {
          oB[g][dt] = __builtin_amdgcn_mfma_f32_16x16x32_bf16(vf0, pfB[g][0],
                                                              oB[g][dt], 0, 0, 0);
          oB[g][dt] = __builtin_amdgcn_mfma_f32_16x16x32_bf16(vf1, pfB[g][1],
                                                              oB[g][dt], 0, 0, 0);
        }
      }
    }
    __builtin_amdgcn_s_setprio(0);
  }

  float linvA[2], linvB[2];
#pragma unroll
  for (int g = 0; g < 2; ++g) {
    float ls = lB[g];
    ls += __shfl_xor(ls, 16);
    ls += __shfl_xor(ls, 32);
    linvB[g] = 1.0f / ls;
    float la = lA[g];
    la += __shfl_xor(la, 16);
    la += __shfl_xor(la, 32);
    linvA[g] = 1.0f / la;
  }

  const int b = bh >> 4, h = bh & 15;
#pragma unroll
  for (int g = 0; g < 2; ++g) {
    const int rowB = t0B + 32 * w + 16 * g + c;
    ushort* dstB = y2 + (size_t)(b * T_ + rowB) * C_ + h * 64;
#pragma unroll
    for (int dt = 0; dt < 4; ++dt) {
      uint2 ov = {cvt_pk_bf16(oB[g][dt][0] * linvB[g], oB[g][dt][1] * linvB[g]),
                  cvt_pk_bf16(oB[g][dt][2] * linvB[g], oB[g][dt][3] * linvB[g])};
      *(uint2*)(dstB + dt * 16 + 4 * quad) = ov;
    }
    const int rowA = t0A + 32 * w + 16 * g + c;
    ushort* dstA = y2 + (size_t)(b * T_ + rowA) * C_ + h * 64;
#pragma unroll
    for (int dt = 0; dt < 4; ++dt) {
      uint2 ov = {cvt_pk_bf16(oA[g][dt][0] * linvA[g], oA[g][dt][1] * linvA[g]),
                  cvt_pk_bf16(oA[g][dt][2] * linvA[g], oA[g][dt][3] * linvA[g])};
      *(uint2*)(dstA + dt * 16 + 4 * quad) = ov;
    }
  }
#undef QK_HALF
#undef SM_HALF
#undef PF_READ
}

// ---------------------------------------------------------------------------
extern "C" void kernel_launch(void* const* d_in, const int* in_sizes, int n_in,
                              void* d_out, int out_size, void* d_ws,
                              size_t ws_size, hipStream_t stream) {
  const float* x = (const float*)d_in[0];
  const float* Wqkv = (const float*)d_in[1];
  const float* bqkv = (const float*)d_in[2];
  const float* Wproj = (const float*)d_in[3];
  const float* bproj = (const float*)d_in[4];
  float* out = (float*)d_out;

  const size_t per = (size_t)B_ * H_ * T_ * D_;  // 8388608
  ushort* q = (ushort*)d_ws;
  ushort* k = q + per;
  ushort* v = k + per;  // [B,H,D,T]
  ushort* y2 = v + per;
  ushort* xb = y2 + per;
  ushort* Wqkvt = xb + per;              // [3072][1024]
  ushort* Wprojt = Wqkvt + 3 * C_ * C_;  // [1024][1024]

  prepass<<<dim3(12288), 256, 0, stream>>>(x, Wqkv, Wproj, xb, Wqkvt, Wprojt);
  gemm_qkv_mfma<<<dim3(24, 64), 256, 0, stream>>>(xb, Wqkvt, bqkv, q, k, v);
  attn<<<dim3(512), 256, 0, stream>>>(q, k, v, y2);
  gemm_proj_mfma<<<dim3(8, 64), 256, 0, stream>>>(y2, Wprojt, bproj, out);
}

// Round 3
// 270.977 us; speedup vs baseline: 1.0116x; 1.0116x over previous
//
#include <hip/hip_runtime.h>
#include <hip/hip_bf16.h>

#define B_ 4
#define T_ 2048
#define C_ 1024
#define H_ 16
#define D_ 64

typedef __attribute__((ext_vector_type(8))) short short8;
typedef __attribute__((ext_vector_type(4))) float f32x4;

// q pre-scale: (1/sqrt(D)) * log2(e) so attn uses raw v_exp_f32 (exp2)
#define QSCALE 0.18033688011112042f

static __device__ __forceinline__ unsigned short f2bf(float f) {
  unsigned u = __float_as_uint(f);
  u += 0x7fff + ((u >> 16) & 1);  // round-to-nearest-even
  return (unsigned short)(u >> 16);
}

// packed bf16 convert: dword = {bf16(lo), bf16(hi)<<16}, RNE (T12 primitive)
static __device__ __forceinline__ unsigned cvt_pk_bf16(float lo, float hi) {
  unsigned r;
  asm("v_cvt_pk_bf16_f32 %0, %1, %2" : "=v"(r) : "v"(lo), "v"(hi));
  return r;
}

static __device__ __forceinline__ float fast_exp2(float x) {
#if __has_builtin(__builtin_amdgcn_exp2f)
  return __builtin_amdgcn_exp2f(x);
#else
  return exp2f(x);
#endif
}

#define GL2LDS16(g, l)                                              \
  __builtin_amdgcn_global_load_lds(                                 \
      (const __attribute__((address_space(1))) void*)(g),           \
      (__attribute__((address_space(3))) void*)(l), 16, 0, 0)

// ---------------------------------------------------------------------------
// Pre-pass: weight transposes only (x conversion is fused into gemm_qkv's
// A-staging). Wqkv transpose: blocks 0..3071; Wproj: 3072..4095.
// ---------------------------------------------------------------------------
__global__ __launch_bounds__(256) void prepass(
    const float* __restrict__ Wq, const float* __restrict__ Wp,
    ushort* __restrict__ Wqt, ushort* __restrict__ Wpt) {
  __shared__ ushort tile[32][33];
  const int bid = blockIdx.x;
  const float* in;
  ushort* out;
  int N, tix;
  if (bid < 3072) {
    in = Wq; out = Wqt; N = 3 * C_; tix = bid;
  } else {
    in = Wp; out = Wpt; N = C_; tix = bid - 3072;
  }
  const int nT = N >> 5;
  const int k0 = (tix / nT) << 5, n0 = (tix % nT) << 5;
  const int r = threadIdx.x >> 3;
  const int c4 = (threadIdx.x & 7) << 2;
  float4 v = *(const float4*)(in + (size_t)(k0 + r) * N + n0 + c4);
  tile[c4 + 0][r] = f2bf(v.x);
  tile[c4 + 1][r] = f2bf(v.y);
  tile[c4 + 2][r] = f2bf(v.z);
  tile[c4 + 3][r] = f2bf(v.w);
  __syncthreads();
  ushort4 o = {tile[r][c4], tile[r][c4 + 1], tile[r][c4 + 2], tile[r][c4 + 3]};
  *(ushort4*)(out + (size_t)(n0 + r) * C_ + k0 + c4) = o;
}

// ---------------------------------------------------------------------------
// LDS XOR-swizzle for BK=64 tiles (128 rows x 128 B). Chunk (16 B) at row r,
// position pos holds global k-chunk x = pos ^ (r & 7).
// ---------------------------------------------------------------------------
static __device__ __forceinline__ void swz_src64(int wave, int lane, int p,
                                                 int& row, int& offU) {
  const int flat = p * 4096 + wave * 1024 + lane * 16;  // byte offset in tile
  row = flat >> 7;                    // 128 B per row
  const int pos = (flat & 127) >> 4;  // chunk index in row
  const int x = pos ^ (row & 7);
  offU = x * 8;  // element offset within the row's K-span
}
static __device__ __forceinline__ int swz_frag64(int r, int quad, int ko) {
  return r * 128 + (((quad | (ko << 2)) ^ (r & 7)) << 4);  // bytes
}

// ---------------------------------------------------------------------------
// MFMA GEMM 1: qkv = x @ Wqkv^T. A (=x) is f32, converted to bf16 in-flight
// during reg-staging (fused prepass); B via global_load_lds. q,k -> [B,H,T,D]
// bf16 (q pre-scaled); v -> [B,H,D,T]. XCD-aware bijective block swizzle.
// ---------------------------------------------------------------------------
__global__ __launch_bounds__(256) void gemm_qkv_mfma(
    const float* __restrict__ X, const ushort* __restrict__ Bt,
    const float* __restrict__ bias, ushort* __restrict__ q,
    ushort* __restrict__ k, ushort* __restrict__ v) {
  __shared__ __align__(16) ushort As[128 * 64];
  __shared__ __align__(16) ushort Bs[128 * 64];
  const int tid = threadIdx.x;
  const int wave = tid >> 6, lane = tid & 63;
  const int c = lane & 15, quad = lane >> 4;
  const int wm = wave & 1, wn = wave >> 1;
  const int bid0 = blockIdx.y * 24 + blockIdx.x;
  const int bid = (bid0 & 7) * 192 + (bid0 >> 3);  // XCD chunking, bijective
  const int m0 = (bid / 24) << 7;
  const int n0 = (bid % 24) << 7;

  int sRow[4], sOff[4];
#pragma unroll
  for (int p = 0; p < 4; ++p) swz_src64(wave, lane, p, sRow[p], sOff[p]);
  int fOffA[2][4], fOffB[2][4];
#pragma unroll
  for (int ko = 0; ko < 2; ++ko) {
#pragma unroll
    for (int i = 0; i < 4; ++i)
      fOffA[ko][i] = swz_frag64(wm * 64 + i * 16 + c, quad, ko);
#pragma unroll
    for (int j = 0; j < 4; ++j)
      fOffB[ko][j] = swz_frag64(wn * 64 + j * 16 + c, quad, ko);
  }

  f32x4 acc[4][4];
#pragma unroll
  for (int i = 0; i < 4; ++i)
#pragma unroll
    for (int j = 0; j < 4; ++j) acc[i][j] = (f32x4){0.f, 0.f, 0.f, 0.f};

  // prefetch A f32 regs for k0 = 0
  float4 aR[4][2];
#pragma unroll
  for (int p = 0; p < 4; ++p) {
    const float* s = X + (size_t)(m0 + sRow[p]) * C_ + sOff[p];
    aR[p][0] = *(const float4*)(s);
    aR[p][1] = *(const float4*)(s + 4);
  }

  for (int k0 = 0; k0 < C_; k0 += 64) {
    __syncthreads();
#pragma unroll
    for (int p = 0; p < 4; ++p) {
      uint4 wv = {cvt_pk_bf16(aR[p][0].x, aR[p][0].y),
                  cvt_pk_bf16(aR[p][0].z, aR[p][0].w),
                  cvt_pk_bf16(aR[p][1].x, aR[p][1].y),
                  cvt_pk_bf16(aR[p][1].z, aR[p][1].w)};
      *(uint4*)((char*)As + p * 4096 + wave * 1024 + lane * 16) = wv;
      GL2LDS16(Bt + (size_t)(n0 + sRow[p]) * C_ + k0 + sOff[p],
               (char*)Bs + p * 4096 + wave * 1024);
    }
    __syncthreads();
    if (k0 + 64 < C_) {  // prefetch next A tile (overlaps compute)
#pragma unroll
      for (int p = 0; p < 4; ++p) {
        const float* s = X + (size_t)(m0 + sRow[p]) * C_ + k0 + 64 + sOff[p];
        aR[p][0] = *(const float4*)(s);
        aR[p][1] = *(const float4*)(s + 4);
      }
    }
#pragma unroll
    for (int ko = 0; ko < 2; ++ko) {
      short8 af[4], bf[4];
#pragma unroll
      for (int i = 0; i < 4; ++i)
        af[i] = *(const short8*)((const char*)As + fOffA[ko][i]);
#pragma unroll
      for (int j = 0; j < 4; ++j)
        bf[j] = *(const short8*)((const char*)Bs + fOffB[ko][j]);
#pragma unroll
      for (int i = 0; i < 4; ++i)
#pragma unroll
        for (int j = 0; j < 4; ++j)
          acc[i][j] = __builtin_amdgcn_mfma_f32_16x16x32_bf16(af[i], bf[j],
                                                              acc[i][j], 0, 0, 0);
    }
  }

  const int s = n0 >> 10;  // uniform per block
  if (s == 2) {
    // v epilogue: [B,H,D,T], reg r spans 4 consecutive t -> ushort4
#pragma unroll
    for (int j = 0; j < 4; ++j) {
      const int n = n0 + wn * 64 + j * 16 + c;
      const int h = (n >> 6) & 15, d = n & 63;
      const float bval = bias[n];
#pragma unroll
      for (int i = 0; i < 4; ++i) {
        const int m = m0 + wm * 64 + i * 16 + quad * 4;
        const int b = m >> 11, t = m & 2047;
        ushort4 pk = {f2bf(acc[i][j][0] + bval), f2bf(acc[i][j][1] + bval),
                      f2bf(acc[i][j][2] + bval), f2bf(acc[i][j][3] + bval)};
        *(ushort4*)(v + (((size_t)((b << 4) + h) << 6) + d) * T_ + t) = pk;
      }
    }
  } else {
    ushort* outp = (s == 0) ? q : k;
    const float sc = (s == 0) ? QSCALE : 1.0f;
#pragma unroll
    for (int j = 0; j < 4; ++j) {
      const int n = n0 + wn * 64 + j * 16 + c;
      const int h = (n >> 6) & 15, d = n & 63;
      const float bval = bias[n];
#pragma unroll
      for (int i = 0; i < 4; ++i) {
#pragma unroll
        for (int r = 0; r < 4; ++r) {
          const int m = m0 + wm * 64 + i * 16 + quad * 4 + r;
          const int b = m >> 11, t = m & 2047;
          outp[(((size_t)((b << 4) + h) << 11) + t) * 64 + d] =
              f2bf((acc[i][j][r] + bval) * sc);
        }
      }
    }
  }
}

// ---------------------------------------------------------------------------
// MFMA GEMM 2: out = y2 @ Wproj + bproj (fp32 out). BK=64, grid (8, 64).
// XCD-aware bijective block swizzle: nwg=512, 64 tiles per XCD chunk.
// ---------------------------------------------------------------------------
__global__ __launch_bounds__(256) void gemm_proj_mfma(
    const ushort* __restrict__ A, const ushort* __restrict__ Bt,
    const float* __restrict__ bias, float* __restrict__ out) {
  __shared__ __align__(16) ushort As[128 * 64];
  __shared__ __align__(16) ushort Bs[128 * 64];
  const int tid = threadIdx.x;
  const int wave = tid >> 6, lane = tid & 63;
  const int c = lane & 15, quad = lane >> 4;
  const int wm = wave & 1, wn = wave >> 1;
  const int bid0 = blockIdx.y * 8 + blockIdx.x;
  const int bid = (bid0 & 7) * 64 + (bid0 >> 3);  // XCD chunking, bijective
  const int m0 = (bid >> 3) << 7;
  const int n0 = (bid & 7) << 7;

  int sRow[4], sOff[4];
#pragma unroll
  for (int p = 0; p < 4; ++p) swz_src64(wave, lane, p, sRow[p], sOff[p]);
  int fOffA[2][4], fOffB[2][4];
#pragma unroll
  for (int ko = 0; ko < 2; ++ko) {
#pragma unroll
    for (int i = 0; i < 4; ++i)
      fOffA[ko][i] = swz_frag64(wm * 64 + i * 16 + c, quad, ko);
#pragma unroll
    for (int j = 0; j < 4; ++j)
      fOffB[ko][j] = swz_frag64(wn * 64 + j * 16 + c, quad, ko);
  }

  f32x4 acc[4][4];
#pragma unroll
  for (int i = 0; i < 4; ++i)
#pragma unroll
    for (int j = 0; j < 4; ++j) acc[i][j] = (f32x4){0.f, 0.f, 0.f, 0.f};

  for (int k0 = 0; k0 < C_; k0 += 64) {
    __syncthreads();
#pragma unroll
    for (int p = 0; p < 4; ++p) {
      GL2LDS16(A + (size_t)(m0 + sRow[p]) * C_ + k0 + sOff[p],
               (char*)As + p * 4096 + wave * 1024);
      GL2LDS16(Bt + (size_t)(n0 + sRow[p]) * C_ + k0 + sOff[p],
               (char*)Bs + p * 4096 + wave * 1024);
    }
    __syncthreads();
#pragma unroll
    for (int ko = 0; ko < 2; ++ko) {
      short8 af[4], bf[4];
#pragma unroll
      for (int i = 0; i < 4; ++i)
        af[i] = *(const short8*)((const char*)As + fOffA[ko][i]);
#pragma unroll
      for (int j = 0; j < 4; ++j)
        bf[j] = *(const short8*)((const char*)Bs + fOffB[ko][j]);
#pragma unroll
      for (int i = 0; i < 4; ++i)
#pragma unroll
        for (int j = 0; j < 4; ++j)
          acc[i][j] = __builtin_amdgcn_mfma_f32_16x16x32_bf16(af[i], bf[j],
                                                              acc[i][j], 0, 0, 0);
    }
  }

#pragma unroll
  for (int j = 0; j < 4; ++j) {
    const int n = n0 + wn * 64 + j * 16 + c;
    const float bval = bias[n];
#pragma unroll
    for (int i = 0; i < 4; ++i) {
#pragma unroll
      for (int r = 0; r < 4; ++r) {
        const int m = m0 + wm * 64 + i * 16 + quad * 4 + r;
        out[(size_t)m * C_ + n] = acc[i][j][r] + bval;
      }
    }
  }
}

// ---------------------------------------------------------------------------
// Flash attention v5 (reverted from v6): transposed-S, 128 queries/block,
// hoisted K-frag reads, cvt_pk bf16 packs, setprio around MFMA clusters.
// 1024 blocks = 4/CU, 16 waves/CU resident. Latency-bound: TLP dominates
// (v6's 512-block pairing regressed 82.5 -> 96 us at 8 waves/CU).
// ---------------------------------------------------------------------------
__global__ __launch_bounds__(256) void attn(const ushort* __restrict__ q,
                                            const ushort* __restrict__ k,
                                            const ushort* __restrict__ v,
                                            ushort* __restrict__ y2) {
  const int qt = 15 - (int)(blockIdx.x >> 6);  // long tiles first
  const int bh = blockIdx.x & 63;
  const int t0 = qt << 7;
  const int w = threadIdx.x >> 6;
  const int lane = threadIdx.x & 63;
  const int c = lane & 15;
  const int quad = lane >> 4;

  const ushort* qp = q + (size_t)bh * T_ * D_;
  const ushort* kp = k + (size_t)bh * T_ * D_;
  const ushort* vp = v + (size_t)bh * D_ * T_;  // [d][t]

  __shared__ __align__(16) ushort Ks[64][72];     // [key][d]
  __shared__ __align__(16) ushort Vs[64][72];     // [d][key]
  __shared__ __align__(16) ushort Ps[4][32][72];  // per-wave [query][key]

  short8 qf[2][2];
#pragma unroll
  for (int g = 0; g < 2; ++g) {
    const ushort* qrow = qp + (size_t)(t0 + 32 * w + 16 * g + c) * D_;
    qf[g][0] = *(const short8*)(qrow + quad * 8);
    qf[g][1] = *(const short8*)(qrow + 32 + quad * 8);
  }

  const int srow = threadIdx.x >> 2;
  const int soff = (threadIdx.x & 3) << 4;

  uint4 ka, kb, va, vb;  // prefetch tile 0
  {
    const ushort* ks = kp + (size_t)srow * D_ + soff;
    const ushort* vs = vp + (size_t)srow * T_ + soff;
    ka = *(const uint4*)(ks);
    kb = *(const uint4*)(ks + 8);
    va = *(const uint4*)(vs);
    vb = *(const uint4*)(vs + 8);
  }

  f32x4 o[2][4];
  float l_i[2] = {0.f, 0.f};
#pragma unroll
  for (int g = 0; g < 2; ++g)
#pragma unroll
    for (int dt = 0; dt < 4; ++dt) o[g][dt] = (f32x4){0.f, 0.f, 0.f, 0.f};

  const int nb = 2 * qt + 2;
  for (int ib = 0; ib < nb; ++ib) {
    const int s0 = ib << 6;
    __syncthreads();
    *(uint4*)(&Ks[srow][soff]) = ka;
    *(uint4*)(&Ks[srow][soff + 8]) = kb;
    *(uint4*)(&Vs[srow][soff]) = va;
    *(uint4*)(&Vs[srow][soff + 8]) = vb;
    __syncthreads();

    if (ib + 1 < nb) {  // prefetch next tile (overlaps compute)
      const int s1 = (ib + 1) << 6;
      const ushort* ks = kp + (size_t)(s1 + srow) * D_ + soff;
      const ushort* vs = vp + (size_t)srow * T_ + s1 + soff;
      ka = *(const uint4*)(ks);
      kb = *(const uint4*)(ks + 8);
      va = *(const uint4*)(vs);
      vb = *(const uint4*)(vs + 8);
    }

    // ---- S^T = K Q^T, K-frags read once, shared across both q-tiles ----
    f32x4 st[2][4];
    __builtin_amdgcn_s_setprio(1);
#pragma unroll
    for (int kt = 0; kt < 4; ++kt) {
      short8 af0 = *(const short8*)(&Ks[kt * 16 + c][quad * 8]);
      short8 af1 = *(const short8*)(&Ks[kt * 16 + c][32 + quad * 8]);
#pragma unroll
      for (int g = 0; g < 2; ++g) {
        f32x4 a = (f32x4){0.f, 0.f, 0.f, 0.f};
        a = __builtin_amdgcn_mfma_f32_16x16x32_bf16(af0, qf[g][0], a, 0, 0, 0);
        a = __builtin_amdgcn_mfma_f32_16x16x32_bf16(af1, qf[g][1], a, 0, 0, 0);
        st[g][kt] = a;
      }
    }
    __builtin_amdgcn_s_setprio(0);

#pragma unroll
    for (int g = 0; g < 2; ++g) {
      const int qbase = t0 + 32 * w + 16 * g;
      if (s0 + 63 > qbase) {  // causal mask for this (wave, g)
#pragma unroll
        for (int kt = 0; kt < 4; ++kt)
#pragma unroll
          for (int r = 0; r < 4; ++r)
            if (s0 + kt * 16 + 4 * quad + r > qbase + c) st[g][kt][r] = -1e30f;
      }
      float lacc = 0.f;
#pragma unroll
      for (int kt = 0; kt < 4; ++kt) {
        float p0 = fast_exp2(st[g][kt][0]);
        float p1 = fast_exp2(st[g][kt][1]);
        float p2 = fast_exp2(st[g][kt][2]);
        float p3 = fast_exp2(st[g][kt][3]);
        lacc += (p0 + p1) + (p2 + p3);
        uint2 pw = {cvt_pk_bf16(p0, p1), cvt_pk_bf16(p2, p3)};
        *(uint2*)(&Ps[w][g * 16 + c][kt * 16 + 4 * quad]) = pw;
      }
      l_i[g] += lacc;
    }

    // ---- O^T += V^T P^T (V-frags shared across both q-tiles) ----
    short8 pf[2][2];
#pragma unroll
    for (int g = 0; g < 2; ++g) {
      pf[g][0] = *(const short8*)(&Ps[w][g * 16 + c][quad * 8]);
      pf[g][1] = *(const short8*)(&Ps[w][g * 16 + c][32 + quad * 8]);
    }
    __builtin_amdgcn_s_setprio(1);
#pragma unroll
    for (int dt = 0; dt < 4; ++dt) {
      short8 vf0 = *(const short8*)(&Vs[dt * 16 + c][quad * 8]);
      short8 vf1 = *(const short8*)(&Vs[dt * 16 + c][32 + quad * 8]);
#pragma unroll
      for (int g = 0; g < 2; ++g) {
        o[g][dt] =
            __builtin_amdgcn_mfma_f32_16x16x32_bf16(vf0, pf[g][0], o[g][dt], 0, 0, 0);
        o[g][dt] =
            __builtin_amdgcn_mfma_f32_16x16x32_bf16(vf1, pf[g][1], o[g][dt], 0, 0, 0);
      }
    }
    __builtin_amdgcn_s_setprio(0);
  }

  float linv[2];
#pragma unroll
  for (int g = 0; g < 2; ++g) {
    float ls = l_i[g];
    ls += __shfl_xor(ls, 16);
    ls += __shfl_xor(ls, 32);
    linv[g] = 1.0f / ls;
  }

  const int b = bh >> 4, h = bh & 15;
#pragma unroll
  for (int g = 0; g < 2; ++g) {
    const int row = t0 + 32 * w + 16 * g + c;
    ushort* dst = y2 + (size_t)(b * T_ + row) * C_ + h * 64;
#pragma unroll
    for (int dt = 0; dt < 4; ++dt) {
      uint2 ov = {cvt_pk_bf16(o[g][dt][0] * linv[g], o[g][dt][1] * linv[g]),
                  cvt_pk_bf16(o[g][dt][2] * linv[g], o[g][dt][3] * linv[g])};
      *(uint2*)(dst + dt * 16 + 4 * quad) = ov;
    }
  }
}

// ---------------------------------------------------------------------------
extern "C" void kernel_launch(void* const* d_in, const int* in_sizes, int n_in,
                              void* d_out, int out_size, void* d_ws,
                              size_t ws_size, hipStream_t stream) {
  const float* x = (const float*)d_in[0];
  const float* Wqkv = (const float*)d_in[1];
  const float* bqkv = (const float*)d_in[2];
  const float* Wproj = (const float*)d_in[3];
  const float* bproj = (const float*)d_in[4];
  float* out = (float*)d_out;

  const size_t per = (size_t)B_ * H_ * T_ * D_;  // 8388608
  ushort* q = (ushort*)d_ws;
  ushort* k = q + per;
  ushort* v = k + per;  // [B,H,D,T]
  ushort* y2 = v + per;
  ushort* Wqkvt = y2 + per;              // [3072][1024]
  ushort* Wprojt = Wqkvt + 3 * C_ * C_;  // [1024][1024]

  prepass<<<dim3(4096), 256, 0, stream>>>(Wqkv, Wproj, Wqkvt, Wprojt);
  gemm_qkv_mfma<<<dim3(24, 64), 256, 0, stream>>>(x, Wqkvt, bqkv, q, k, v);
  attn<<<dim3(1024), 256, 0, stream>>>(q, k, v, y2);
  gemm_proj_mfma<<<dim3(8, 64), 256, 0, stream>>>(y2, Wprojt, bproj, out);
}

// Round 4
// 261.368 us; speedup vs baseline: 1.0488x; 1.0368x over previous
//
#include <hip/hip_runtime.h>
#include <hip/hip_bf16.h>

#define B_ 4
#define T_ 2048
#define C_ 1024
#define H_ 16
#define D_ 64

typedef __attribute__((ext_vector_type(8))) short short8;
typedef __attribute__((ext_vector_type(4))) float f32x4;

// q pre-scale: (1/sqrt(D)) * log2(e) so attn uses raw v_exp_f32 (exp2)
#define QSCALE 0.18033688011112042f

static __device__ __forceinline__ unsigned short f2bf(float f) {
  unsigned u = __float_as_uint(f);
  u += 0x7fff + ((u >> 16) & 1);  // round-to-nearest-even
  return (unsigned short)(u >> 16);
}

// packed bf16 convert: dword = {bf16(lo), bf16(hi)<<16}, RNE (T12 primitive)
static __device__ __forceinline__ unsigned cvt_pk_bf16(float lo, float hi) {
  unsigned r;
  asm("v_cvt_pk_bf16_f32 %0, %1, %2" : "=v"(r) : "v"(lo), "v"(hi));
  return r;
}

static __device__ __forceinline__ float fast_exp2(float x) {
#if __has_builtin(__builtin_amdgcn_exp2f)
  return __builtin_amdgcn_exp2f(x);
#else
  return exp2f(x);
#endif
}

#define GL2LDS16(g, l)                                              \
  __builtin_amdgcn_global_load_lds(                                 \
      (const __attribute__((address_space(1))) void*)(g),           \
      (__attribute__((address_space(3))) void*)(l), 16, 0, 0)

// ---------------------------------------------------------------------------
// Fused pre-pass: x->bf16 (blocks 0..8191), Wqkv transpose (8192..11263),
// Wproj transpose (11264..12287).
// ---------------------------------------------------------------------------
__global__ __launch_bounds__(256) void prepass(
    const float* __restrict__ x, const float* __restrict__ Wq,
    const float* __restrict__ Wp, ushort* __restrict__ xb,
    ushort* __restrict__ Wqt, ushort* __restrict__ Wpt) {
  __shared__ ushort tile[32][33];
  const int bid = blockIdx.x;
  if (bid < 8192) {
    const size_t i = ((size_t)bid * 256 + threadIdx.x) * 4;
    float4 vv = *(const float4*)(x + i);
    ushort4 o = {f2bf(vv.x), f2bf(vv.y), f2bf(vv.z), f2bf(vv.w)};
    *(ushort4*)(xb + i) = o;
    return;
  }
  const float* in;
  ushort* out;
  int N, tix;
  if (bid < 8192 + 3072) {
    in = Wq; out = Wqt; N = 3 * C_; tix = bid - 8192;
  } else {
    in = Wp; out = Wpt; N = C_; tix = bid - 11264;
  }
  const int nT = N >> 5;
  const int k0 = (tix / nT) << 5, n0 = (tix % nT) << 5;
  const int r = threadIdx.x >> 3;
  const int c4 = (threadIdx.x & 7) << 2;
  float4 v = *(const float4*)(in + (size_t)(k0 + r) * N + n0 + c4);
  tile[c4 + 0][r] = f2bf(v.x);
  tile[c4 + 1][r] = f2bf(v.y);
  tile[c4 + 2][r] = f2bf(v.z);
  tile[c4 + 3][r] = f2bf(v.w);
  __syncthreads();
  ushort4 o = {tile[r][c4], tile[r][c4 + 1], tile[r][c4 + 2], tile[r][c4 + 3]};
  *(ushort4*)(out + (size_t)(n0 + r) * C_ + k0 + c4) = o;
}

// ---------------------------------------------------------------------------
// LDS XOR-swizzle for BK=64 tiles (128 rows x 128 B). Chunk (16 B) at row r,
// position pos holds global k-chunk x = pos ^ (r & 7).
// ---------------------------------------------------------------------------
static __device__ __forceinline__ void swz_src64(int wave, int lane, int p,
                                                 int& row, int& offU) {
  const int flat = p * 4096 + wave * 1024 + lane * 16;  // byte offset in tile
  row = flat >> 7;                    // 128 B per row
  const int pos = (flat & 127) >> 4;  // chunk index in row
  const int x = pos ^ (row & 7);
  offU = x * 8;  // element offset within the row's K-span
}
static __device__ __forceinline__ int swz_frag64(int r, int quad, int ko) {
  return r * 128 + (((quad | (ko << 2)) ^ (r & 7)) << 4);  // bytes
}

// ---------------------------------------------------------------------------
// MFMA GEMM 1: qkv. q,k -> [B,H,T,D] bf16 (q pre-scaled); v -> [B,H,D,T].
// bf16 A via global_load_lds (round-1 structure; f32-A fusion regressed
// 83->99us: kernel moves at fixed ~1.5 TB/s so extra A-bytes cost linearly).
// XCD-aware bijective block swizzle (T1).
// ---------------------------------------------------------------------------
__global__ __launch_bounds__(256) void gemm_qkv_mfma(
    const ushort* __restrict__ A, const ushort* __restrict__ Bt,
    const float* __restrict__ bias, ushort* __restrict__ q,
    ushort* __restrict__ k, ushort* __restrict__ v) {
  __shared__ __align__(16) ushort As[128 * 64];
  __shared__ __align__(16) ushort Bs[128 * 64];
  const int tid = threadIdx.x;
  const int wave = tid >> 6, lane = tid & 63;
  const int c = lane & 15, quad = lane >> 4;
  const int wm = wave & 1, wn = wave >> 1;
  const int bid0 = blockIdx.y * 24 + blockIdx.x;
  const int bid = (bid0 & 7) * 192 + (bid0 >> 3);  // XCD chunking, bijective
  const int m0 = (bid / 24) << 7;
  const int n0 = (bid % 24) << 7;

  int sRow[4], sOff[4];
#pragma unroll
  for (int p = 0; p < 4; ++p) swz_src64(wave, lane, p, sRow[p], sOff[p]);
  int fOffA[2][4], fOffB[2][4];
#pragma unroll
  for (int ko = 0; ko < 2; ++ko) {
#pragma unroll
    for (int i = 0; i < 4; ++i)
      fOffA[ko][i] = swz_frag64(wm * 64 + i * 16 + c, quad, ko);
#pragma unroll
    for (int j = 0; j < 4; ++j)
      fOffB[ko][j] = swz_frag64(wn * 64 + j * 16 + c, quad, ko);
  }

  f32x4 acc[4][4];
#pragma unroll
  for (int i = 0; i < 4; ++i)
#pragma unroll
    for (int j = 0; j < 4; ++j) acc[i][j] = (f32x4){0.f, 0.f, 0.f, 0.f};

  for (int k0 = 0; k0 < C_; k0 += 64) {
    __syncthreads();
#pragma unroll
    for (int p = 0; p < 4; ++p) {
      GL2LDS16(A + (size_t)(m0 + sRow[p]) * C_ + k0 + sOff[p],
               (char*)As + p * 4096 + wave * 1024);
      GL2LDS16(Bt + (size_t)(n0 + sRow[p]) * C_ + k0 + sOff[p],
               (char*)Bs + p * 4096 + wave * 1024);
    }
    __syncthreads();
#pragma unroll
    for (int ko = 0; ko < 2; ++ko) {
      short8 af[4], bf[4];
#pragma unroll
      for (int i = 0; i < 4; ++i)
        af[i] = *(const short8*)((const char*)As + fOffA[ko][i]);
#pragma unroll
      for (int j = 0; j < 4; ++j)
        bf[j] = *(const short8*)((const char*)Bs + fOffB[ko][j]);
#pragma unroll
      for (int i = 0; i < 4; ++i)
#pragma unroll
        for (int j = 0; j < 4; ++j)
          acc[i][j] = __builtin_amdgcn_mfma_f32_16x16x32_bf16(af[i], bf[j],
                                                              acc[i][j], 0, 0, 0);
    }
  }

  const int s = n0 >> 10;  // uniform per block
  if (s == 2) {
    // v epilogue: [B,H,D,T], reg r spans 4 consecutive t -> ushort4
#pragma unroll
    for (int j = 0; j < 4; ++j) {
      const int n = n0 + wn * 64 + j * 16 + c;
      const int h = (n >> 6) & 15, d = n & 63;
      const float bval = bias[n];
#pragma unroll
      for (int i = 0; i < 4; ++i) {
        const int m = m0 + wm * 64 + i * 16 + quad * 4;
        const int b = m >> 11, t = m & 2047;
        ushort4 pk = {f2bf(acc[i][j][0] + bval), f2bf(acc[i][j][1] + bval),
                      f2bf(acc[i][j][2] + bval), f2bf(acc[i][j][3] + bval)};
        *(ushort4*)(v + (((size_t)((b << 4) + h) << 6) + d) * T_ + t) = pk;
      }
    }
  } else {
    ushort* outp = (s == 0) ? q : k;
    const float sc = (s == 0) ? QSCALE : 1.0f;
#pragma unroll
    for (int j = 0; j < 4; ++j) {
      const int n = n0 + wn * 64 + j * 16 + c;
      const int h = (n >> 6) & 15, d = n & 63;
      const float bval = bias[n];
#pragma unroll
      for (int i = 0; i < 4; ++i) {
#pragma unroll
        for (int r = 0; r < 4; ++r) {
          const int m = m0 + wm * 64 + i * 16 + quad * 4 + r;
          const int b = m >> 11, t = m & 2047;
          outp[(((size_t)((b << 4) + h) << 11) + t) * 64 + d] =
              f2bf((acc[i][j][r] + bval) * sc);
        }
      }
    }
  }
}

// ---------------------------------------------------------------------------
// MFMA GEMM 2: out = y2 @ Wproj + bproj (fp32 out). BK=64, grid (8, 64).
// XCD-aware bijective block swizzle: nwg=512, 64 tiles per XCD chunk.
// ---------------------------------------------------------------------------
__global__ __launch_bounds__(256) void gemm_proj_mfma(
    const ushort* __restrict__ A, const ushort* __restrict__ Bt,
    const float* __restrict__ bias, float* __restrict__ out) {
  __shared__ __align__(16) ushort As[128 * 64];
  __shared__ __align__(16) ushort Bs[128 * 64];
  const int tid = threadIdx.x;
  const int wave = tid >> 6, lane = tid & 63;
  const int c = lane & 15, quad = lane >> 4;
  const int wm = wave & 1, wn = wave >> 1;
  const int bid0 = blockIdx.y * 8 + blockIdx.x;
  const int bid = (bid0 & 7) * 64 + (bid0 >> 3);  // XCD chunking, bijective
  const int m0 = (bid >> 3) << 7;
  const int n0 = (bid & 7) << 7;

  int sRow[4], sOff[4];
#pragma unroll
  for (int p = 0; p < 4; ++p) swz_src64(wave, lane, p, sRow[p], sOff[p]);
  int fOffA[2][4], fOffB[2][4];
#pragma unroll
  for (int ko = 0; ko < 2; ++ko) {
#pragma unroll
    for (int i = 0; i < 4; ++i)
      fOffA[ko][i] = swz_frag64(wm * 64 + i * 16 + c, quad, ko);
#pragma unroll
    for (int j = 0; j < 4; ++j)
      fOffB[ko][j] = swz_frag64(wn * 64 + j * 16 + c, quad, ko);
  }

  f32x4 acc[4][4];
#pragma unroll
  for (int i = 0; i < 4; ++i)
#pragma unroll
    for (int j = 0; j < 4; ++j) acc[i][j] = (f32x4){0.f, 0.f, 0.f, 0.f};

  for (int k0 = 0; k0 < C_; k0 += 64) {
    __syncthreads();
#pragma unroll
    for (int p = 0; p < 4; ++p) {
      GL2LDS16(A + (size_t)(m0 + sRow[p]) * C_ + k0 + sOff[p],
               (char*)As + p * 4096 + wave * 1024);
      GL2LDS16(Bt + (size_t)(n0 + sRow[p]) * C_ + k0 + sOff[p],
               (char*)Bs + p * 4096 + wave * 1024);
    }
    __syncthreads();
#pragma unroll
    for (int ko = 0; ko < 2; ++ko) {
      short8 af[4], bf[4];
#pragma unroll
      for (int i = 0; i < 4; ++i)
        af[i] = *(const short8*)((const char*)As + fOffA[ko][i]);
#pragma unroll
      for (int j = 0; j < 4; ++j)
        bf[j] = *(const short8*)((const char*)Bs + fOffB[ko][j]);
#pragma unroll
      for (int i = 0; i < 4; ++i)
#pragma unroll
        for (int j = 0; j < 4; ++j)
          acc[i][j] = __builtin_amdgcn_mfma_f32_16x16x32_bf16(af[i], bf[j],
                                                              acc[i][j], 0, 0, 0);
    }
  }

#pragma unroll
  for (int j = 0; j < 4; ++j) {
    const int n = n0 + wn * 64 + j * 16 + c;
    const float bval = bias[n];
#pragma unroll
    for (int i = 0; i < 4; ++i) {
#pragma unroll
      for (int r = 0; r < 4; ++r) {
        const int m = m0 + wm * 64 + i * 16 + quad * 4 + r;
        out[(size_t)m * C_ + n] = acc[i][j][r] + bval;
      }
    }
  }
}

// ---------------------------------------------------------------------------
// Flash attention v7: v5 structure (4 blocks/CU, 16 waves/CU) + CU-balanced
// qt mapping. Dispatch round-robins 8 XCDs, so CU slot gets bids
// {b, b+256, b+512, b+768}; with qt = tab[bid>>6] each CU's four blocks
// draw one qt from each row-group with column sums == 30 -> every CU does
// exactly 68 KV-tile units (was 56..80, hottest CU +17.6%).
// ---------------------------------------------------------------------------
__global__ __launch_bounds__(256) void attn(const ushort* __restrict__ q,
                                            const ushort* __restrict__ k,
                                            const ushort* __restrict__ v,
                                            ushort* __restrict__ y2) {
  static const int qt_tab[16] = {15, 14, 13, 12, 8, 9, 10, 11,
                                 4,  5,  6,  7,  3, 2, 1,  0};
  const int qt = qt_tab[blockIdx.x >> 6];
  const int bh = blockIdx.x & 63;
  const int t0 = qt << 7;
  const int w = threadIdx.x >> 6;
  const int lane = threadIdx.x & 63;
  const int c = lane & 15;
  const int quad = lane >> 4;

  const ushort* qp = q + (size_t)bh * T_ * D_;
  const ushort* kp = k + (size_t)bh * T_ * D_;
  const ushort* vp = v + (size_t)bh * D_ * T_;  // [d][t]

  __shared__ __align__(16) ushort Ks[64][72];     // [key][d]
  __shared__ __align__(16) ushort Vs[64][72];     // [d][key]
  __shared__ __align__(16) ushort Ps[4][32][72];  // per-wave [query][key]

  short8 qf[2][2];
#pragma unroll
  for (int g = 0; g < 2; ++g) {
    const ushort* qrow = qp + (size_t)(t0 + 32 * w + 16 * g + c) * D_;
    qf[g][0] = *(const short8*)(qrow + quad * 8);
    qf[g][1] = *(const short8*)(qrow + 32 + quad * 8);
  }

  const int srow = threadIdx.x >> 2;
  const int soff = (threadIdx.x & 3) << 4;

  uint4 ka, kb, va, vb;  // prefetch tile 0
  {
    const ushort* ks = kp + (size_t)srow * D_ + soff;
    const ushort* vs = vp + (size_t)srow * T_ + soff;
    ka = *(const uint4*)(ks);
    kb = *(const uint4*)(ks + 8);
    va = *(const uint4*)(vs);
    vb = *(const uint4*)(vs + 8);
  }

  f32x4 o[2][4];
  float l_i[2] = {0.f, 0.f};
#pragma unroll
  for (int g = 0; g < 2; ++g)
#pragma unroll
    for (int dt = 0; dt < 4; ++dt) o[g][dt] = (f32x4){0.f, 0.f, 0.f, 0.f};

  const int nb = 2 * qt + 2;
  for (int ib = 0; ib < nb; ++ib) {
    const int s0 = ib << 6;
    __syncthreads();
    *(uint4*)(&Ks[srow][soff]) = ka;
    *(uint4*)(&Ks[srow][soff + 8]) = kb;
    *(uint4*)(&Vs[srow][soff]) = va;
    *(uint4*)(&Vs[srow][soff + 8]) = vb;
    __syncthreads();

    if (ib + 1 < nb) {  // prefetch next tile (overlaps compute)
      const int s1 = (ib + 1) << 6;
      const ushort* ks = kp + (size_t)(s1 + srow) * D_ + soff;
      const ushort* vs = vp + (size_t)srow * T_ + s1 + soff;
      ka = *(const uint4*)(ks);
      kb = *(const uint4*)(ks + 8);
      va = *(const uint4*)(vs);
      vb = *(const uint4*)(vs + 8);
    }

    // ---- S^T = K Q^T, K-frags read once, shared across both q-tiles ----
    f32x4 st[2][4];
    __builtin_amdgcn_s_setprio(1);
#pragma unroll
    for (int kt = 0; kt < 4; ++kt) {
      short8 af0 = *(const short8*)(&Ks[kt * 16 + c][quad * 8]);
      short8 af1 = *(const short8*)(&Ks[kt * 16 + c][32 + quad * 8]);
#pragma unroll
      for (int g = 0; g < 2; ++g) {
        f32x4 a = (f32x4){0.f, 0.f, 0.f, 0.f};
        a = __builtin_amdgcn_mfma_f32_16x16x32_bf16(af0, qf[g][0], a, 0, 0, 0);
        a = __builtin_amdgcn_mfma_f32_16x16x32_bf16(af1, qf[g][1], a, 0, 0, 0);
        st[g][kt] = a;
      }
    }
    __builtin_amdgcn_s_setprio(0);

#pragma unroll
    for (int g = 0; g < 2; ++g) {
      const int qbase = t0 + 32 * w + 16 * g;
      if (s0 + 63 > qbase) {  // causal mask for this (wave, g)
#pragma unroll
        for (int kt = 0; kt < 4; ++kt)
#pragma unroll
          for (int r = 0; r < 4; ++r)
            if (s0 + kt * 16 + 4 * quad + r > qbase + c) st[g][kt][r] = -1e30f;
      }
      float lacc = 0.f;
#pragma unroll
      for (int kt = 0; kt < 4; ++kt) {
        float p0 = fast_exp2(st[g][kt][0]);
        float p1 = fast_exp2(st[g][kt][1]);
        float p2 = fast_exp2(st[g][kt][2]);
        float p3 = fast_exp2(st[g][kt][3]);
        lacc += (p0 + p1) + (p2 + p3);
        uint2 pw = {cvt_pk_bf16(p0, p1), cvt_pk_bf16(p2, p3)};
        *(uint2*)(&Ps[w][g * 16 + c][kt * 16 + 4 * quad]) = pw;
      }
      l_i[g] += lacc;
    }

    // ---- O^T += V^T P^T (V-frags shared across both q-tiles) ----
    short8 pf[2][2];
#pragma unroll
    for (int g = 0; g < 2; ++g) {
      pf[g][0] = *(const short8*)(&Ps[w][g * 16 + c][quad * 8]);
      pf[g][1] = *(const short8*)(&Ps[w][g * 16 + c][32 + quad * 8]);
    }
    __builtin_amdgcn_s_setprio(1);
#pragma unroll
    for (int dt = 0; dt < 4; ++dt) {
      short8 vf0 = *(const short8*)(&Vs[dt * 16 + c][quad * 8]);
      short8 vf1 = *(const short8*)(&Vs[dt * 16 + c][32 + quad * 8]);
#pragma unroll
      for (int g = 0; g < 2; ++g) {
        o[g][dt] =
            __builtin_amdgcn_mfma_f32_16x16x32_bf16(vf0, pf[g][0], o[g][dt], 0, 0, 0);
        o[g][dt] =
            __builtin_amdgcn_mfma_f32_16x16x32_bf16(vf1, pf[g][1], o[g][dt], 0, 0, 0);
      }
    }
    __builtin_amdgcn_s_setprio(0);
  }

  float linv[2];
#pragma unroll
  for (int g = 0; g < 2; ++g) {
    float ls = l_i[g];
    ls += __shfl_xor(ls, 16);
    ls += __shfl_xor(ls, 32);
    linv[g] = 1.0f / ls;
  }

  const int b = bh >> 4, h = bh & 15;
#pragma unroll
  for (int g = 0; g < 2; ++g) {
    const int row = t0 + 32 * w + 16 * g + c;
    ushort* dst = y2 + (size_t)(b * T_ + row) * C_ + h * 64;
#pragma unroll
    for (int dt = 0; dt < 4; ++dt) {
      uint2 ov = {cvt_pk_bf16(o[g][dt][0] * linv[g], o[g][dt][1] * linv[g]),
                  cvt_pk_bf16(o[g][dt][2] * linv[g], o[g][dt][3] * linv[g])};
      *(uint2*)(dst + dt * 16 + 4 * quad) = ov;
    }
  }
}

// ---------------------------------------------------------------------------
extern "C" void kernel_launch(void* const* d_in, const int* in_sizes, int n_in,
                              void* d_out, int out_size, void* d_ws,
                              size_t ws_size, hipStream_t stream) {
  const float* x = (const float*)d_in[0];
  const float* Wqkv = (const float*)d_in[1];
  const float* bqkv = (const float*)d_in[2];
  const float* Wproj = (const float*)d_in[3];
  const float* bproj = (const float*)d_in[4];
  float* out = (float*)d_out;

  const size_t per = (size_t)B_ * H_ * T_ * D_;  // 8388608
  ushort* q = (ushort*)d_ws;
  ushort* k = q + per;
  ushort* v = k + per;  // [B,H,D,T]
  ushort* y2 = v + per;
  ushort* xb = y2 + per;
  ushort* Wqkvt = xb + per;              // [3072][1024]
  ushort* Wprojt = Wqkvt + 3 * C_ * C_;  // [1024][1024]

  prepass<<<dim3(12288), 256, 0, stream>>>(x, Wqkv, Wproj, xb, Wqkvt, Wprojt);
  gemm_qkv_mfma<<<dim3(24, 64), 256, 0, stream>>>(xb, Wqkvt, bqkv, q, k, v);
  attn<<<dim3(1024), 256, 0, stream>>>(q, k, v, y2);
  gemm_proj_mfma<<<dim3(8, 64), 256, 0, stream>>>(y2, Wprojt, bproj, out);
}

// Round 5
// 244.151 us; speedup vs baseline: 1.1228x; 1.0705x over previous
//
#include <hip/hip_runtime.h>
#include <hip/hip_bf16.h>

#define B_ 4
#define T_ 2048
#define C_ 1024
#define H_ 16
#define D_ 64

typedef __attribute__((ext_vector_type(8))) short short8;
typedef __attribute__((ext_vector_type(4))) float f32x4;

// q pre-scale: (1/sqrt(D)) * log2(e) so attn uses raw v_exp_f32 (exp2)
#define QSCALE 0.18033688011112042f

static __device__ __forceinline__ unsigned short f2bf(float f) {
  unsigned u = __float_as_uint(f);
  u += 0x7fff + ((u >> 16) & 1);  // round-to-nearest-even
  return (unsigned short)(u >> 16);
}

// packed bf16 convert: dword = {bf16(lo), bf16(hi)<<16}, RNE (T12 primitive)
static __device__ __forceinline__ unsigned cvt_pk_bf16(float lo, float hi) {
  unsigned r;
  asm("v_cvt_pk_bf16_f32 %0, %1, %2" : "=v"(r) : "v"(lo), "v"(hi));
  return r;
}

static __device__ __forceinline__ float fast_exp2(float x) {
#if __has_builtin(__builtin_amdgcn_exp2f)
  return __builtin_amdgcn_exp2f(x);
#else
  return exp2f(x);
#endif
}

#define GL2LDS16(g, l)                                              \
  __builtin_amdgcn_global_load_lds(                                 \
      (const __attribute__((address_space(1))) void*)(g),           \
      (__attribute__((address_space(3))) void*)(l), 16, 0, 0)

// ---------------------------------------------------------------------------
// Fused pre-pass: x->bf16 (blocks 0..8191), Wqkv transpose (8192..11263),
// Wproj transpose (11264..12287).
// ---------------------------------------------------------------------------
__global__ __launch_bounds__(256) void prepass(
    const float* __restrict__ x, const float* __restrict__ Wq,
    const float* __restrict__ Wp, ushort* __restrict__ xb,
    ushort* __restrict__ Wqt, ushort* __restrict__ Wpt) {
  __shared__ ushort tile[32][33];
  const int bid = blockIdx.x;
  if (bid < 8192) {
    const size_t i = ((size_t)bid * 256 + threadIdx.x) * 4;
    float4 vv = *(const float4*)(x + i);
    ushort4 o = {f2bf(vv.x), f2bf(vv.y), f2bf(vv.z), f2bf(vv.w)};
    *(ushort4*)(xb + i) = o;
    return;
  }
  const float* in;
  ushort* out;
  int N, tix;
  if (bid < 8192 + 3072) {
    in = Wq; out = Wqt; N = 3 * C_; tix = bid - 8192;
  } else {
    in = Wp; out = Wpt; N = C_; tix = bid - 11264;
  }
  const int nT = N >> 5;
  const int k0 = (tix / nT) << 5, n0 = (tix % nT) << 5;
  const int r = threadIdx.x >> 3;
  const int c4 = (threadIdx.x & 7) << 2;
  float4 v = *(const float4*)(in + (size_t)(k0 + r) * N + n0 + c4);
  tile[c4 + 0][r] = f2bf(v.x);
  tile[c4 + 1][r] = f2bf(v.y);
  tile[c4 + 2][r] = f2bf(v.z);
  tile[c4 + 3][r] = f2bf(v.w);
  __syncthreads();
  ushort4 o = {tile[r][c4], tile[r][c4 + 1], tile[r][c4 + 2], tile[r][c4 + 3]};
  *(ushort4*)(out + (size_t)(n0 + r) * C_ + k0 + c4) = o;
}

// ---------------------------------------------------------------------------
// LDS XOR-swizzle for 128 B rows staged via global_load_lds. Chunk (16 B) at
// row r, position pos holds global chunk x = pos ^ (r & 7).
// ---------------------------------------------------------------------------
static __device__ __forceinline__ void swz_src64(int wave, int lane, int p,
                                                 int& row, int& offU) {
  const int flat = p * 4096 + wave * 1024 + lane * 16;  // byte offset in tile
  row = flat >> 7;                    // 128 B per row
  const int pos = (flat & 127) >> 4;  // chunk index in row
  const int x = pos ^ (row & 7);
  offU = x * 8;  // element offset within the row's span
}
static __device__ __forceinline__ int swz_frag64(int r, int quad, int ko) {
  return r * 128 + (((quad | (ko << 2)) ^ (r & 7)) << 4);  // bytes
}

// ---------------------------------------------------------------------------
// MFMA GEMM 1: qkv. q,k -> [B,H,T,D] bf16 (q pre-scaled); v -> [B,H,D,T].
// XCD-aware bijective block swizzle (T1).
// ---------------------------------------------------------------------------
__global__ __launch_bounds__(256) void gemm_qkv_mfma(
    const ushort* __restrict__ A, const ushort* __restrict__ Bt,
    const float* __restrict__ bias, ushort* __restrict__ q,
    ushort* __restrict__ k, ushort* __restrict__ v) {
  __shared__ __align__(16) ushort As[128 * 64];
  __shared__ __align__(16) ushort Bs[128 * 64];
  const int tid = threadIdx.x;
  const int wave = tid >> 6, lane = tid & 63;
  const int c = lane & 15, quad = lane >> 4;
  const int wm = wave & 1, wn = wave >> 1;
  const int bid0 = blockIdx.y * 24 + blockIdx.x;
  const int bid = (bid0 & 7) * 192 + (bid0 >> 3);  // XCD chunking, bijective
  const int m0 = (bid / 24) << 7;
  const int n0 = (bid % 24) << 7;

  int sRow[4], sOff[4];
#pragma unroll
  for (int p = 0; p < 4; ++p) swz_src64(wave, lane, p, sRow[p], sOff[p]);
  int fOffA[2][4], fOffB[2][4];
#pragma unroll
  for (int ko = 0; ko < 2; ++ko) {
#pragma unroll
    for (int i = 0; i < 4; ++i)
      fOffA[ko][i] = swz_frag64(wm * 64 + i * 16 + c, quad, ko);
#pragma unroll
    for (int j = 0; j < 4; ++j)
      fOffB[ko][j] = swz_frag64(wn * 64 + j * 16 + c, quad, ko);
  }

  f32x4 acc[4][4];
#pragma unroll
  for (int i = 0; i < 4; ++i)
#pragma unroll
    for (int j = 0; j < 4; ++j) acc[i][j] = (f32x4){0.f, 0.f, 0.f, 0.f};

  for (int k0 = 0; k0 < C_; k0 += 64) {
    __syncthreads();
#pragma unroll
    for (int p = 0; p < 4; ++p) {
      GL2LDS16(A + (size_t)(m0 + sRow[p]) * C_ + k0 + sOff[p],
               (char*)As + p * 4096 + wave * 1024);
      GL2LDS16(Bt + (size_t)(n0 + sRow[p]) * C_ + k0 + sOff[p],
               (char*)Bs + p * 4096 + wave * 1024);
    }
    __syncthreads();
#pragma unroll
    for (int ko = 0; ko < 2; ++ko) {
      short8 af[4], bf[4];
#pragma unroll
      for (int i = 0; i < 4; ++i)
        af[i] = *(const short8*)((const char*)As + fOffA[ko][i]);
#pragma unroll
      for (int j = 0; j < 4; ++j)
        bf[j] = *(const short8*)((const char*)Bs + fOffB[ko][j]);
#pragma unroll
      for (int i = 0; i < 4; ++i)
#pragma unroll
        for (int j = 0; j < 4; ++j)
          acc[i][j] = __builtin_amdgcn_mfma_f32_16x16x32_bf16(af[i], bf[j],
                                                              acc[i][j], 0, 0, 0);
    }
  }

  const int s = n0 >> 10;  // uniform per block
  if (s == 2) {
    // v epilogue: [B,H,D,T], reg r spans 4 consecutive t -> ushort4
#pragma unroll
    for (int j = 0; j < 4; ++j) {
      const int n = n0 + wn * 64 + j * 16 + c;
      const int h = (n >> 6) & 15, d = n & 63;
      const float bval = bias[n];
#pragma unroll
      for (int i = 0; i < 4; ++i) {
        const int m = m0 + wm * 64 + i * 16 + quad * 4;
        const int b = m >> 11, t = m & 2047;
        ushort4 pk = {f2bf(acc[i][j][0] + bval), f2bf(acc[i][j][1] + bval),
                      f2bf(acc[i][j][2] + bval), f2bf(acc[i][j][3] + bval)};
        *(ushort4*)(v + (((size_t)((b << 4) + h) << 6) + d) * T_ + t) = pk;
      }
    }
  } else {
    ushort* outp = (s == 0) ? q : k;
    const float sc = (s == 0) ? QSCALE : 1.0f;
#pragma unroll
    for (int j = 0; j < 4; ++j) {
      const int n = n0 + wn * 64 + j * 16 + c;
      const int h = (n >> 6) & 15, d = n & 63;
      const float bval = bias[n];
#pragma unroll
      for (int i = 0; i < 4; ++i) {
#pragma unroll
        for (int r = 0; r < 4; ++r) {
          const int m = m0 + wm * 64 + i * 16 + quad * 4 + r;
          const int b = m >> 11, t = m & 2047;
          outp[(((size_t)((b << 4) + h) << 11) + t) * 64 + d] =
              f2bf((acc[i][j][r] + bval) * sc);
        }
      }
    }
  }
}

// ---------------------------------------------------------------------------
// MFMA GEMM 2: out = y2 @ Wproj + bproj (fp32 out). BK=64, grid (8, 64).
// XCD-aware bijective block swizzle: nwg=512, 64 tiles per XCD chunk.
// ---------------------------------------------------------------------------
__global__ __launch_bounds__(256) void gemm_proj_mfma(
    const ushort* __restrict__ A, const ushort* __restrict__ Bt,
    const float* __restrict__ bias, float* __restrict__ out) {
  __shared__ __align__(16) ushort As[128 * 64];
  __shared__ __align__(16) ushort Bs[128 * 64];
  const int tid = threadIdx.x;
  const int wave = tid >> 6, lane = tid & 63;
  const int c = lane & 15, quad = lane >> 4;
  const int wm = wave & 1, wn = wave >> 1;
  const int bid0 = blockIdx.y * 8 + blockIdx.x;
  const int bid = (bid0 & 7) * 64 + (bid0 >> 3);  // XCD chunking, bijective
  const int m0 = (bid >> 3) << 7;
  const int n0 = (bid & 7) << 7;

  int sRow[4], sOff[4];
#pragma unroll
  for (int p = 0; p < 4; ++p) swz_src64(wave, lane, p, sRow[p], sOff[p]);
  int fOffA[2][4], fOffB[2][4];
#pragma unroll
  for (int ko = 0; ko < 2; ++ko) {
#pragma unroll
    for (int i = 0; i < 4; ++i)
      fOffA[ko][i] = swz_frag64(wm * 64 + i * 16 + c, quad, ko);
#pragma unroll
    for (int j = 0; j < 4; ++j)
      fOffB[ko][j] = swz_frag64(wn * 64 + j * 16 + c, quad, ko);
  }

  f32x4 acc[4][4];
#pragma unroll
  for (int i = 0; i < 4; ++i)
#pragma unroll
    for (int j = 0; j < 4; ++j) acc[i][j] = (f32x4){0.f, 0.f, 0.f, 0.f};

  for (int k0 = 0; k0 < C_; k0 += 64) {
    __syncthreads();
#pragma unroll
    for (int p = 0; p < 4; ++p) {
      GL2LDS16(A + (size_t)(m0 + sRow[p]) * C_ + k0 + sOff[p],
               (char*)As + p * 4096 + wave * 1024);
      GL2LDS16(Bt + (size_t)(n0 + sRow[p]) * C_ + k0 + sOff[p],
               (char*)Bs + p * 4096 + wave * 1024);
    }
    __syncthreads();
#pragma unroll
    for (int ko = 0; ko < 2; ++ko) {
      short8 af[4], bf[4];
#pragma unroll
      for (int i = 0; i < 4; ++i)
        af[i] = *(const short8*)((const char*)As + fOffA[ko][i]);
#pragma unroll
      for (int j = 0; j < 4; ++j)
        bf[j] = *(const short8*)((const char*)Bs + fOffB[ko][j]);
#pragma unroll
      for (int i = 0; i < 4; ++i)
#pragma unroll
        for (int j = 0; j < 4; ++j)
          acc[i][j] = __builtin_amdgcn_mfma_f32_16x16x32_bf16(af[i], bf[j],
                                                              acc[i][j], 0, 0, 0);
    }
  }

#pragma unroll
  for (int j = 0; j < 4; ++j) {
    const int n = n0 + wn * 64 + j * 16 + c;
    const float bval = bias[n];
#pragma unroll
    for (int i = 0; i < 4; ++i) {
#pragma unroll
      for (int r = 0; r < 4; ++r) {
        const int m = m0 + wm * 64 + i * 16 + quad * 4 + r;
        out[(size_t)m * C_ + n] = acc[i][j][r] + bval;
      }
    }
  }
}

// ---------------------------------------------------------------------------
// Flash attention v8: async double-buffered K/V staging via global_load_lds
// (pre-swizzled source + swizzled frag reads, T21-correct), ONE barrier per
// KV-tile, stage-in-flight during compute (T3-minimum). LDS 50 KB -> 3
// blocks/CU resident, 1024 blocks -> 256-block HW queue backfills the causal
// drain (long-qt first, shortest work dispatched last).
// ---------------------------------------------------------------------------
__global__ __launch_bounds__(256) void attn(const ushort* __restrict__ q,
                                            const ushort* __restrict__ k,
                                            const ushort* __restrict__ v,
                                            ushort* __restrict__ y2) {
  const int qt = 15 - (int)(blockIdx.x >> 6);  // long tiles first
  const int bh = blockIdx.x & 63;
  const int t0 = qt << 7;
  const int w = threadIdx.x >> 6;
  const int lane = threadIdx.x & 63;
  const int c = lane & 15;
  const int quad = lane >> 4;

  const ushort* qp = q + (size_t)bh * T_ * D_;
  const ushort* kp = k + (size_t)bh * T_ * D_;
  const ushort* vp = v + (size_t)bh * D_ * T_;  // [d][t]

  __shared__ __align__(16) ushort Ks[2][64 * 64];  // [key][d], swizzled rows
  __shared__ __align__(16) ushort Vs[2][64 * 64];  // [d][key], swizzled rows
  __shared__ __align__(16) ushort Ps[4][32][72];   // per-wave [query][key]

  short8 qf[2][2];
#pragma unroll
  for (int g = 0; g < 2; ++g) {
    const ushort* qrow = qp + (size_t)(t0 + 32 * w + 16 * g + c) * D_;
    qf[g][0] = *(const short8*)(qrow + quad * 8);
    qf[g][1] = *(const short8*)(qrow + 32 + quad * 8);
  }

  // staging geometry: each tile = 64 rows x 128 B = 8 KB; thread stages 16 B
  // at flat = p*4096 + tid*16 (p=0,1); source chunk pre-swizzled so that the
  // linear GL2LDS dest yields chunk x = pos ^ (row&7) at position pos.
  int sRow[2], sX[2];
#pragma unroll
  for (int p = 0; p < 2; ++p) {
    const int flat = p * 4096 + (int)threadIdx.x * 16;
    sRow[p] = flat >> 7;
    sX[p] = (((flat & 127) >> 4) ^ (sRow[p] & 7)) * 8;  // ushort offset
  }

#define STAGE(buf, s0s)                                                   \
  do {                                                                    \
    _Pragma("unroll") for (int p = 0; p < 2; ++p) {                       \
      GL2LDS16(kp + (size_t)((s0s) + sRow[p]) * D_ + sX[p],               \
               (char*)Ks[buf] + p * 4096 + w * 1024);                     \
      GL2LDS16(vp + (size_t)sRow[p] * T_ + (s0s) + sX[p],                 \
               (char*)Vs[buf] + p * 4096 + w * 1024);                     \
    }                                                                     \
  } while (0)

  f32x4 o[2][4];
  float l_i[2] = {0.f, 0.f};
#pragma unroll
  for (int g = 0; g < 2; ++g)
#pragma unroll
    for (int dt = 0; dt < 4; ++dt) o[g][dt] = (f32x4){0.f, 0.f, 0.f, 0.f};

  const int nb = 2 * qt + 2;
  STAGE(0, 0);  // prologue: tile 0 in flight
  int cur = 0;

  for (int ib = 0; ib < nb; ++ib) {
    const int s0 = ib << 6;
    // compiler drains vmcnt+lgkmcnt before s_barrier -> buf[cur] visible
    __syncthreads();
    if (ib + 1 < nb) STAGE(cur ^ 1, s0 + 64);  // in flight across compute

    // ---- S^T = K Q^T, K-frags read once, shared across both q-tiles ----
    f32x4 st[2][4];
    __builtin_amdgcn_s_setprio(1);
#pragma unroll
    for (int kt = 0; kt < 4; ++kt) {
      const char* kb = (const char*)Ks[cur];
      short8 af0 = *(const short8*)(kb + swz_frag64(kt * 16 + c, quad, 0));
      short8 af1 = *(const short8*)(kb + swz_frag64(kt * 16 + c, quad, 1));
#pragma unroll
      for (int g = 0; g < 2; ++g) {
        f32x4 a = (f32x4){0.f, 0.f, 0.f, 0.f};
        a = __builtin_amdgcn_mfma_f32_16x16x32_bf16(af0, qf[g][0], a, 0, 0, 0);
        a = __builtin_amdgcn_mfma_f32_16x16x32_bf16(af1, qf[g][1], a, 0, 0, 0);
        st[g][kt] = a;
      }
    }
    __builtin_amdgcn_s_setprio(0);

#pragma unroll
    for (int g = 0; g < 2; ++g) {
      const int qbase = t0 + 32 * w + 16 * g;
      if (s0 + 63 > qbase) {  // causal mask for this (wave, g)
#pragma unroll
        for (int kt = 0; kt < 4; ++kt)
#pragma unroll
          for (int r = 0; r < 4; ++r)
            if (s0 + kt * 16 + 4 * quad + r > qbase + c) st[g][kt][r] = -1e30f;
      }
      float lacc = 0.f;
#pragma unroll
      for (int kt = 0; kt < 4; ++kt) {
        float p0 = fast_exp2(st[g][kt][0]);
        float p1 = fast_exp2(st[g][kt][1]);
        float p2 = fast_exp2(st[g][kt][2]);
        float p3 = fast_exp2(st[g][kt][3]);
        lacc += (p0 + p1) + (p2 + p3);
        uint2 pw = {cvt_pk_bf16(p0, p1), cvt_pk_bf16(p2, p3)};
        *(uint2*)(&Ps[w][g * 16 + c][kt * 16 + 4 * quad]) = pw;
      }
      l_i[g] += lacc;
    }

    // ---- O^T += V^T P^T (V-frags shared across both q-tiles) ----
    short8 pf[2][2];
#pragma unroll
    for (int g = 0; g < 2; ++g) {
      pf[g][0] = *(const short8*)(&Ps[w][g * 16 + c][quad * 8]);
      pf[g][1] = *(const short8*)(&Ps[w][g * 16 + c][32 + quad * 8]);
    }
    __builtin_amdgcn_s_setprio(1);
#pragma unroll
    for (int dt = 0; dt < 4; ++dt) {
      const char* vb = (const char*)Vs[cur];
      short8 vf0 = *(const short8*)(vb + swz_frag64(dt * 16 + c, quad, 0));
      short8 vf1 = *(const short8*)(vb + swz_frag64(dt * 16 + c, quad, 1));
#pragma unroll
      for (int g = 0; g < 2; ++g) {
        o[g][dt] =
            __builtin_amdgcn_mfma_f32_16x16x32_bf16(vf0, pf[g][0], o[g][dt], 0, 0, 0);
        o[g][dt] =
            __builtin_amdgcn_mfma_f32_16x16x32_bf16(vf1, pf[g][1], o[g][dt], 0, 0, 0);
      }
    }
    __builtin_amdgcn_s_setprio(0);
    cur ^= 1;
  }
#undef STAGE

  float linv[2];
#pragma unroll
  for (int g = 0; g < 2; ++g) {
    float ls = l_i[g];
    ls += __shfl_xor(ls, 16);
    ls += __shfl_xor(ls, 32);
    linv[g] = 1.0f / ls;
  }

  const int b = bh >> 4, h = bh & 15;
#pragma unroll
  for (int g = 0; g < 2; ++g) {
    const int row = t0 + 32 * w + 16 * g + c;
    ushort* dst = y2 + (size_t)(b * T_ + row) * C_ + h * 64;
#pragma unroll
    for (int dt = 0; dt < 4; ++dt) {
      uint2 ov = {cvt_pk_bf16(o[g][dt][0] * linv[g], o[g][dt][1] * linv[g]),
                  cvt_pk_bf16(o[g][dt][2] * linv[g], o[g][dt][3] * linv[g])};
      *(uint2*)(dst + dt * 16 + 4 * quad) = ov;
    }
  }
}

// ---------------------------------------------------------------------------
extern "C" void kernel_launch(void* const* d_in, const int* in_sizes, int n_in,
                              void* d_out, int out_size, void* d_ws,
                              size_t ws_size, hipStream_t stream) {
  const float* x = (const float*)d_in[0];
  const float* Wqkv = (const float*)d_in[1];
  const float* bqkv = (const float*)d_in[2];
  const float* Wproj = (const float*)d_in[3];
  const float* bproj = (const float*)d_in[4];
  float* out = (float*)d_out;

  const size_t per = (size_t)B_ * H_ * T_ * D_;  // 8388608
  ushort* q = (ushort*)d_ws;
  ushort* k = q + per;
  ushort* v = k + per;  // [B,H,D,T]
  ushort* y2 = v + per;
  ushort* xb = y2 + per;
  ushort* Wqkvt = xb + per;              // [3072][1024]
  ushort* Wprojt = Wqkvt + 3 * C_ * C_;  // [1024][1024]

  prepass<<<dim3(12288), 256, 0, stream>>>(x, Wqkv, Wproj, xb, Wqkvt, Wprojt);
  gemm_qkv_mfma<<<dim3(24, 64), 256, 0, stream>>>(xb, Wqkvt, bqkv, q, k, v);
  attn<<<dim3(1024), 256, 0, stream>>>(q, k, v, y2);
  gemm_proj_mfma<<<dim3(8, 64), 256, 0, stream>>>(y2, Wprojt, bproj, out);
}